// Round 6
// baseline (185.038 us; speedup 1.0000x reference)
//
#include <hip/hip_runtime.h>

#define NTHH 4            // stored theta rows (GL-8 folded by theta-mirror)
#define NPHH 8            // stored phi cols (16 folded by phi -> phi+pi)
#define NROW (NTHH*NPHH)  // 32 stored grid rows; each serves 4 quadrature points
#define YP   28           // Y row stride, padded 25->28
#define L2C  25
#define CCH  128
#define PADR 144          // padded LDS row stride: 4 quarters x 36 floats

static __device__ __host__ __forceinline__ int lof_of(int i) {
  return (i >= 16) ? 4 : (i >= 9) ? 3 : (i >= 4) ? 2 : (i >= 1) ? 1 : 0;
}
static __device__ __forceinline__ int pidx(int c) {   // padded channel index
  return (c >> 5) * 36 + (c & 31);
}

// ---------------------------------------------------------------------------
// Compile-time Y table (constexpr; lives in read-only global/constant memory).
// TP reads it with wave-uniform indices -> scalar loads, no LDS copy needed.
// ---------------------------------------------------------------------------
static constexpr double csqrt_(double x) {
  double y = x > 1.0 ? x : 1.0;
  for (int i = 0; i < 60; ++i) y = 0.5 * (y + x / y);
  return y;
}

struct alignas(16) YTabT { float y[NROW * YP]; float wq[4]; };

static constexpr YTabT build_ytab() {
  YTabT T{};
  constexpr double CT[4] = {-0.9602898564975363, -0.7966664774136267,
                            -0.5255324099163290, -0.1834346424956498};
  constexpr double WT[4] = { 0.1012285362903763,  0.2223810344533745,
                             0.3137066458778873,  0.3626837833783620};
  constexpr double PI = 3.14159265358979323846264338327950288;
  const double FACT[9] = {1,1,2,6,24,120,720,5040,40320};
  double c8[16] = {}, s8[16] = {};
  {
    const double c2 = csqrt_(0.5);
    const double c1 = csqrt_((1.0 + c2) * 0.5), s1 = csqrt_((1.0 - c2) * 0.5);
    double ck = 1.0, sk = 0.0;
    for (int k = 0; k < 16; ++k) {
      c8[k] = ck; s8[k] = sk;
      const double cn = ck * c1 - sk * s1;
      const double sn = sk * c1 + ck * s1;
      ck = cn; sk = sn;
    }
  }
  const double SQ2 = csqrt_(2.0);
  double NN[5][5] = {};
  for (int l = 0; l <= 4; ++l)
    for (int am = 0; am <= l; ++am)
      NN[l][am] = csqrt_((2.0*l + 1.0) / (4.0*PI) * FACT[l-am] / FACT[l+am]);
  for (int g = 0; g < NROW; ++g) {
    const int tt = g / NPHH, pp = g % NPHH;
    const double x = CT[tt], st = csqrt_(1.0 - x*x);
    for (int i = 0; i < L2C; ++i) {
      int l = 0; while ((l+1)*(l+1) <= i) ++l;
      const int m = i - l*l - l, am = m < 0 ? -m : m;
      double pmm = 1.0;
      for (int mm = 1; mm <= am; ++mm) pmm *= -(2.0*mm - 1.0) * st;
      double plm = pmm;
      if (l > am) {
        double pa = pmm, pb = (2.0*am + 1.0) * x * pmm;
        for (int ll = am + 2; ll <= l; ++ll) {
          const double pc = ((2.0*ll - 1.0)*x*pb - (ll + am - 1.0)*pa) / (double)(ll - am);
          pa = pb; pb = pc;
        }
        plm = pb;
      }
      const int k = (am * pp) & 15;
      double ang = 1.0, pref = 1.0;
      if (m > 0)      { ang = c8[k]; pref = SQ2; }
      else if (m < 0) { ang = s8[k]; pref = SQ2; }
      T.y[g*YP + i] = (float)(pref * NN[l][am] * plm * ang);
    }
    for (int i = L2C; i < YP; ++i) T.y[g*YP + i] = 0.0f;
  }
  for (int t = 0; t < 4; ++t) T.wq[t] = (float)(WT[t] * (2.0*PI/16.0));
  return T;
}

__device__ constexpr YTabT G_Y = build_ytab();

// block-wide sum over 256 threads (4 waves of 64)
__device__ __forceinline__ float block_sum(float v, float* scr, int t) {
#pragma unroll
  for (int o = 32; o > 0; o >>= 1) v += __shfl_down(v, o, 64);
  __syncthreads();
  if ((t & 63) == 0) scr[t >> 6] = v;
  __syncthreads();
  return scr[0] + scr[1] + scr[2] + scr[3];
}

// ---------------------------------------------------------------------------
// Per-degree SO3 linear GEMV. 4-way c-split in lane bits 4-5, 2 outputs
// (d, d+64) per thread, shfl_xor(16/32) quarter reduce.
// FINAL: + bias + global residual -> out.
// ---------------------------------------------------------------------------
template<int L, bool FINAL>
__device__ __forceinline__ void so3lin(const float* __restrict__ sIn,
                                       float* __restrict__ sOut,
                                       const float* __restrict__ W,
                                       const float* __restrict__ bias,
                                       const float* __restrict__ xres,
                                       float* __restrict__ gout, int t) {
  constexpr int NC = 2*L + 1, I0 = L*L;
  const int dlo = (t & 15) | ((t >> 2) & 48);   // lane low bits + wave*16
  const int q   = (t >> 4) & 3;                 // c-quarter = lane bits 4-5
  float acc0[NC], acc1[NC];
#pragma unroll
  for (int j = 0; j < NC; ++j) { acc0[j] = 0.f; acc1[j] = 0.f; }
  const float* w = W + L*CCH*CCH;
  const float* arow0 = sIn + I0*PADR + q*36;
  for (int cc = 0; cc < 32; cc += 4) {
    const float* wc = w + (q*32 + cc)*CCH;
    const float wa0 = wc[dlo],        wb0 = wc[dlo+64];
    const float wa1 = wc[CCH+dlo],    wb1 = wc[CCH+dlo+64];
    const float wa2 = wc[2*CCH+dlo],  wb2 = wc[2*CCH+dlo+64];
    const float wa3 = wc[3*CCH+dlo],  wb3 = wc[3*CCH+dlo+64];
#pragma unroll
    for (int j = 0; j < NC; ++j) {
      const float4 a = *(const float4*)&arow0[j*PADR + cc];
      acc0[j] = fmaf(a.w,wa3, fmaf(a.z,wa2, fmaf(a.y,wa1, fmaf(a.x,wa0, acc0[j]))));
      acc1[j] = fmaf(a.w,wb3, fmaf(a.z,wb2, fmaf(a.y,wb1, fmaf(a.x,wb0, acc1[j]))));
    }
  }
#pragma unroll
  for (int j = 0; j < NC; ++j) {
    acc0[j] += __shfl_xor(acc0[j], 16, 64); acc0[j] += __shfl_xor(acc0[j], 32, 64);
    acc1[j] += __shfl_xor(acc1[j], 16, 64); acc1[j] += __shfl_xor(acc1[j], 32, 64);
  }
  if (q == 0) {
#pragma unroll
    for (int j = 0; j < NC; ++j) {
      float r0 = acc0[j], r1 = acc1[j];
      if (L == 0) { r0 += bias[dlo]; r1 += bias[dlo+64]; }
      if (FINAL) {
        gout[(I0+j)*CCH + dlo]    = r0 + xres[(I0+j)*CCH + dlo];
        gout[(I0+j)*CCH + dlo+64] = r1 + xres[(I0+j)*CCH + dlo+64];
      } else {
        sOut[(I0+j)*PADR + pidx(dlo)]    = r0;
        sOut[(I0+j)*PADR + pidx(dlo+64)] = r1;
      }
    }
  }
}

// ---------------------------------------------------------------------------
// Fused: LN -> Linear1 -> Gaunt self-TP (theta+phi folded exact grid) ->
// Linear2 -> +residual.  One block per node. LDS = 28.8 KB -> 5 blocks/CU.
// ---------------------------------------------------------------------------
__global__ __launch_bounds__(256, 5)
void fused_gaunt_kernel(const float* __restrict__ x,
                        const float* __restrict__ norm_w,
                        const float* __restrict__ norm_b,
                        const float* __restrict__ w1,
                        const float* __restrict__ b1,
                        const float* __restrict__ tp_w,
                        const float* __restrict__ w2,
                        const float* __restrict__ b2,
                        float* __restrict__ out) {
  __shared__ float sA[L2C*PADR];   // 14400 B (x, then normalized h in place)
  __shared__ float sB[L2C*PADR];   // 14400 B (lin1 out / TP in place)
  __shared__ float sScr[4];

  const int t = threadIdx.x;
  const int n = blockIdx.x;
  const float* xn = x   + (size_t)n * (L2C*CCH);
  float*       on = out + (size_t)n * (L2C*CCH);

  // ---- stage: x -> sA (padded quarters)
  for (int e = t; e < (L2C*CCH)/4; e += 256) {
    const int i = e >> 5, c = (e & 31) << 2;
    *(float4*)&sA[i*PADR + pidx(c)] = ((const float4*)xn)[e];
  }
  __syncthreads();

  // ---- LN statistics
  float v0 = (t < CCH) ? sA[pidx(t)] : 0.f;
  const float mean0 = block_sum(v0, sScr, t) * (1.f/CCH);
  float ss = 0.f;
  for (int e = t; e < L2C*CCH; e += 256) {
    const float val = sA[(e >> 7)*PADR + pidx(e & 127)];
    ss = fmaf(val, val, ss);
  }
  const float s2 = block_sum(ss, sScr, t);
  const float var = (s2 - CCH*mean0*mean0) * (1.f/(L2C*CCH));
  const float inv = rsqrtf(var + 1e-5f);

  // ---- materialize normalized h in place
  for (int e = t; e < L2C*CCH; e += 256) {
    const int i = e >> 7, c = e & 127;
    float val = sA[i*PADR + pidx(c)];
    if (i == 0) val -= mean0;
    val *= inv * norm_w[lof_of(i)*CCH + c];
    if (i == 0) val += norm_b[c];
    sA[i*PADR + pidx(c)] = val;
  }
  __syncthreads();

  // ---- SO3Linear 1 (disjoint sB rows per degree; one sync at end)
  so3lin<0,false>(sA, sB, w1, b1, nullptr, nullptr, t);
  so3lin<1,false>(sA, sB, w1, b1, nullptr, nullptr, t);
  so3lin<2,false>(sA, sB, w1, b1, nullptr, nullptr, t);
  so3lin<3,false>(sA, sB, w1, b1, nullptr, nullptr, t);
  so3lin<4,false>(sA, sB, w1, b1, nullptr, nullptr, t);
  __syncthreads();

  // ---- Gaunt self-TP: 128-point exact grid, folded 4x by theta-mirror
  // (sgn_i = (-1)^(l+|m|)) and phi->phi+pi (sig_i = (-1)^|m|).
  // Classes: A(+,+)={0,4,6,8,16,18,20,22,24} B(+,-)={1,3,9,11,13,15}
  //          C(-,+)={2,10,12,14}             D(-,-)={5,7,17,19,21,23}
  // f(+t,p)=A+B+C+D  f(+t,p+8)=A-B+C-D  f(-t,p)=A+B-C-D  f(-t,p+8)=A-B-C+D
  // Y rows come straight from constexpr G_Y with wave-uniform indices ->
  // scalar (s_load) reads; no LDS copy.
  {
    const int c = t & 127;
    const int gg = t >> 7;                                   // wave-uniform
    const int ggu = __builtin_amdgcn_readfirstlane(gg);      // force SGPR
    float u[25], y[25];
#pragma unroll
    for (int i = 0; i < 25; ++i) { u[i] = sB[i*PADR + pidx(c)]; y[i] = 0.f; }
    __syncthreads();   // all u reads complete before sB partial overwrite
#pragma unroll
    for (int tt2 = 0; tt2 < 2; ++tt2) {
      const int tt = ggu*2 + tt2;
      const float wq = G_Y.wq[tt];
      for (int pp = 0; pp < NPHH; ++pp) {
        const float* yr = &G_Y.y[(tt*NPHH + pp)*YP];
        // class partial dot-products (A split for ILP)
        float A0 = u[ 0]*yr[0];
        A0 = fmaf(u[ 4], yr[ 4], A0); A0 = fmaf(u[ 6], yr[ 6], A0);
        A0 = fmaf(u[ 8], yr[ 8], A0); A0 = fmaf(u[24], yr[24], A0);
        float A1 = u[16]*yr[16];
        A1 = fmaf(u[18], yr[18], A1); A1 = fmaf(u[20], yr[20], A1);
        A1 = fmaf(u[22], yr[22], A1);
        float B = u[ 1]*yr[1];
        B = fmaf(u[ 3], yr[ 3], B); B = fmaf(u[ 9], yr[ 9], B);
        B = fmaf(u[11], yr[11], B); B = fmaf(u[13], yr[13], B);
        B = fmaf(u[15], yr[15], B);
        float C = u[ 2]*yr[2];
        C = fmaf(u[10], yr[10], C); C = fmaf(u[12], yr[12], C);
        C = fmaf(u[14], yr[14], C);
        float D = u[ 5]*yr[5];
        D = fmaf(u[ 7], yr[ 7], D); D = fmaf(u[17], yr[17], D);
        D = fmaf(u[19], yr[19], D); D = fmaf(u[21], yr[21], D);
        D = fmaf(u[23], yr[23], D);
        const float A  = A0 + A1;
        const float tp = A + B, tm = A - B, up = C + D, um = C - D;
        const float f1 = tp + up, f3 = tp - up;   // (+t,p), (-t,p)
        const float f2 = tm + um, f4 = tm - um;   // (+t,p+8), (-t,p+8)
        const float s1 = f1*f1, s2v = f2*f2, s3 = f3*f3, s4 = f4*f4;
        const float p = s1 + s2v, q = s1 - s2v, r = s3 + s4, t4 = s3 - s4;
        const float cA = wq*(p + r), cC = wq*(p - r);
        const float cB = wq*(q + t4), cD = wq*(q - t4);
        y[ 0] = fmaf(cA, yr[ 0], y[ 0]); y[ 1] = fmaf(cB, yr[ 1], y[ 1]);
        y[ 2] = fmaf(cC, yr[ 2], y[ 2]); y[ 3] = fmaf(cB, yr[ 3], y[ 3]);
        y[ 4] = fmaf(cA, yr[ 4], y[ 4]); y[ 5] = fmaf(cD, yr[ 5], y[ 5]);
        y[ 6] = fmaf(cA, yr[ 6], y[ 6]); y[ 7] = fmaf(cD, yr[ 7], y[ 7]);
        y[ 8] = fmaf(cA, yr[ 8], y[ 8]); y[ 9] = fmaf(cB, yr[ 9], y[ 9]);
        y[10] = fmaf(cC, yr[10], y[10]); y[11] = fmaf(cB, yr[11], y[11]);
        y[12] = fmaf(cC, yr[12], y[12]); y[13] = fmaf(cB, yr[13], y[13]);
        y[14] = fmaf(cC, yr[14], y[14]); y[15] = fmaf(cB, yr[15], y[15]);
        y[16] = fmaf(cA, yr[16], y[16]); y[17] = fmaf(cD, yr[17], y[17]);
        y[18] = fmaf(cA, yr[18], y[18]); y[19] = fmaf(cD, yr[19], y[19]);
        y[20] = fmaf(cA, yr[20], y[20]); y[21] = fmaf(cD, yr[21], y[21]);
        y[22] = fmaf(cA, yr[22], y[22]); y[23] = fmaf(cD, yr[23], y[23]);
        y[24] = fmaf(cA, yr[24], y[24]);
      }
    }
    if (gg == 1) {
#pragma unroll
      for (int i = 0; i < 25; ++i) sB[i*PADR + pidx(c)] = y[i];
    }
    __syncthreads();
    if (gg == 0) {
#pragma unroll
      for (int i = 0; i < 25; ++i)
        sB[i*PADR + pidx(c)] = (y[i] + sB[i*PADR + pidx(c)]) * tp_w[lof_of(i)*CCH + c];
    }
    __syncthreads();
  }

  // ---- SO3Linear 2 + bias(l=0) + residual (global re-read) -> out
  so3lin<0,true>(sB, nullptr, w2, b2, xn, on, t);
  so3lin<1,true>(sB, nullptr, w2, b2, xn, on, t);
  so3lin<2,true>(sB, nullptr, w2, b2, xn, on, t);
  so3lin<3,true>(sB, nullptr, w2, b2, xn, on, t);
  so3lin<4,true>(sB, nullptr, w2, b2, xn, on, t);
}

extern "C" void kernel_launch(void* const* d_in, const int* in_sizes, int n_in,
                              void* d_out, int out_size, void* d_ws, size_t ws_size,
                              hipStream_t stream) {
  (void)n_in; (void)out_size; (void)d_ws; (void)ws_size;
  const float* x      = (const float*)d_in[0];
  // d_in[1] = batch (int32) -- only feeds drop_path(rate=0), unused
  const float* norm_w = (const float*)d_in[2];
  const float* norm_b = (const float*)d_in[3];
  const float* w1     = (const float*)d_in[4];
  const float* b1     = (const float*)d_in[5];
  const float* tp_w   = (const float*)d_in[6];
  const float* w2     = (const float*)d_in[7];
  const float* b2     = (const float*)d_in[8];
  float* out  = (float*)d_out;

  const int N = in_sizes[0] / (L2C*CCH);

  fused_gaunt_kernel<<<dim3(N), dim3(256), 0, stream>>>(
      x, norm_w, norm_b, w1, b1, tp_w, w2, b2, out);
}

// Round 8
// 183.745 us; speedup vs baseline: 1.0070x; 1.0070x over previous
//
#include <hip/hip_runtime.h>

#define NTHH 4            // stored theta rows (GL-8 folded by theta-mirror)
#define NPHH 8            // stored phi cols (16 folded by phi -> phi+pi)
#define NROW (NTHH*NPHH)  // 32 stored grid rows; each serves 4 quadrature points
#define YP   28           // Y row stride, padded 25->28
#define L2C  25
#define CCH  128
#define PADR 144          // padded LDS row stride: 4 quarters x 36 floats

static __device__ __host__ __forceinline__ int lof_of(int i) {
  return (i >= 16) ? 4 : (i >= 9) ? 3 : (i >= 4) ? 2 : (i >= 1) ? 1 : 0;
}
static __device__ __forceinline__ int pidx(int c) {   // padded channel index
  return (c >> 5) * 36 + (c & 31);
}

// ---------------------------------------------------------------------------
// Compile-time Y table (constexpr; lives in read-only global/constant memory).
// TP reads it with wave-uniform indices -> scalar loads, no LDS copy needed.
// ---------------------------------------------------------------------------
static constexpr double csqrt_(double x) {
  double y = x > 1.0 ? x : 1.0;
  for (int i = 0; i < 60; ++i) y = 0.5 * (y + x / y);
  return y;
}

struct alignas(16) YTabT { float y[NROW * YP]; float wq[4]; };

static constexpr YTabT build_ytab() {
  YTabT T{};
  constexpr double CT[4] = {-0.9602898564975363, -0.7966664774136267,
                            -0.5255324099163290, -0.1834346424956498};
  constexpr double WT[4] = { 0.1012285362903763,  0.2223810344533745,
                             0.3137066458778873,  0.3626837833783620};
  constexpr double PI = 3.14159265358979323846264338327950288;
  const double FACT[9] = {1,1,2,6,24,120,720,5040,40320};
  double c8[16] = {}, s8[16] = {};
  {
    const double c2 = csqrt_(0.5);
    const double c1 = csqrt_((1.0 + c2) * 0.5), s1 = csqrt_((1.0 - c2) * 0.5);
    double ck = 1.0, sk = 0.0;
    for (int k = 0; k < 16; ++k) {
      c8[k] = ck; s8[k] = sk;
      const double cn = ck * c1 - sk * s1;
      const double sn = sk * c1 + ck * s1;
      ck = cn; sk = sn;
    }
  }
  const double SQ2 = csqrt_(2.0);
  double NN[5][5] = {};
  for (int l = 0; l <= 4; ++l)
    for (int am = 0; am <= l; ++am)
      NN[l][am] = csqrt_((2.0*l + 1.0) / (4.0*PI) * FACT[l-am] / FACT[l+am]);
  for (int g = 0; g < NROW; ++g) {
    const int tt = g / NPHH, pp = g % NPHH;
    const double x = CT[tt], st = csqrt_(1.0 - x*x);
    for (int i = 0; i < L2C; ++i) {
      int l = 0; while ((l+1)*(l+1) <= i) ++l;
      const int m = i - l*l - l, am = m < 0 ? -m : m;
      double pmm = 1.0;
      for (int mm = 1; mm <= am; ++mm) pmm *= -(2.0*mm - 1.0) * st;
      double plm = pmm;
      if (l > am) {
        double pa = pmm, pb = (2.0*am + 1.0) * x * pmm;
        for (int ll = am + 2; ll <= l; ++ll) {
          const double pc = ((2.0*ll - 1.0)*x*pb - (ll + am - 1.0)*pa) / (double)(ll - am);
          pa = pb; pb = pc;
        }
        plm = pb;
      }
      const int k = (am * pp) & 15;
      double ang = 1.0, pref = 1.0;
      if (m > 0)      { ang = c8[k]; pref = SQ2; }
      else if (m < 0) { ang = s8[k]; pref = SQ2; }
      T.y[g*YP + i] = (float)(pref * NN[l][am] * plm * ang);
    }
    for (int i = L2C; i < YP; ++i) T.y[g*YP + i] = 0.0f;
  }
  for (int t = 0; t < 4; ++t) T.wq[t] = (float)(WT[t] * (2.0*PI/16.0));
  return T;
}

__device__ constexpr YTabT G_Y = build_ytab();

// block-wide sum over 256 threads (4 waves of 64)
__device__ __forceinline__ float block_sum(float v, float* scr, int t) {
#pragma unroll
  for (int o = 32; o > 0; o >>= 1) v += __shfl_down(v, o, 64);
  __syncthreads();
  if ((t & 63) == 0) scr[t >> 6] = v;
  __syncthreads();
  return scr[0] + scr[1] + scr[2] + scr[3];
}

// ---------------------------------------------------------------------------
// Per-degree SO3 linear GEMV. 4-way c-split in lane bits 4-5, 2 outputs
// (d, d+64) per thread, shfl_xor(16/32) quarter reduce.
// FINAL: + bias + global residual -> out.
// ---------------------------------------------------------------------------
template<int L, bool FINAL>
__device__ __forceinline__ void so3lin(const float* __restrict__ sIn,
                                       float* __restrict__ sOut,
                                       const float* __restrict__ W,
                                       const float* __restrict__ bias,
                                       const float* __restrict__ xres,
                                       float* __restrict__ gout, int t) {
  constexpr int NC = 2*L + 1, I0 = L*L;
  const int dlo = (t & 15) | ((t >> 2) & 48);   // lane low bits + wave*16
  const int q   = (t >> 4) & 3;                 // c-quarter = lane bits 4-5
  float acc0[NC], acc1[NC];
#pragma unroll
  for (int j = 0; j < NC; ++j) { acc0[j] = 0.f; acc1[j] = 0.f; }
  const float* w = W + L*CCH*CCH;
  const float* arow0 = sIn + I0*PADR + q*36;
  for (int cc = 0; cc < 32; cc += 4) {
    const float* wc = w + (q*32 + cc)*CCH;
    const float wa0 = wc[dlo],        wb0 = wc[dlo+64];
    const float wa1 = wc[CCH+dlo],    wb1 = wc[CCH+dlo+64];
    const float wa2 = wc[2*CCH+dlo],  wb2 = wc[2*CCH+dlo+64];
    const float wa3 = wc[3*CCH+dlo],  wb3 = wc[3*CCH+dlo+64];
#pragma unroll
    for (int j = 0; j < NC; ++j) {
      const float4 a = *(const float4*)&arow0[j*PADR + cc];
      acc0[j] = fmaf(a.w,wa3, fmaf(a.z,wa2, fmaf(a.y,wa1, fmaf(a.x,wa0, acc0[j]))));
      acc1[j] = fmaf(a.w,wb3, fmaf(a.z,wb2, fmaf(a.y,wb1, fmaf(a.x,wb0, acc1[j]))));
    }
  }
#pragma unroll
  for (int j = 0; j < NC; ++j) {
    acc0[j] += __shfl_xor(acc0[j], 16, 64); acc0[j] += __shfl_xor(acc0[j], 32, 64);
    acc1[j] += __shfl_xor(acc1[j], 16, 64); acc1[j] += __shfl_xor(acc1[j], 32, 64);
  }
  if (q == 0) {
#pragma unroll
    for (int j = 0; j < NC; ++j) {
      float r0 = acc0[j], r1 = acc1[j];
      if (L == 0) { r0 += bias[dlo]; r1 += bias[dlo+64]; }
      if (FINAL) {
        gout[(I0+j)*CCH + dlo]    = r0 + xres[(I0+j)*CCH + dlo];
        gout[(I0+j)*CCH + dlo+64] = r1 + xres[(I0+j)*CCH + dlo+64];
      } else {
        sOut[(I0+j)*PADR + pidx(dlo)]    = r0;
        sOut[(I0+j)*PADR + pidx(dlo+64)] = r1;
      }
    }
  }
}

// ---------------------------------------------------------------------------
// Fused: LN -> Linear1 -> Gaunt self-TP (theta+phi folded exact grid) ->
// Linear2 -> +residual.  One block per node. LDS = 28.8 KB.
// launch_bounds(256,4): VGPR budget 128 so the TP's u[25]+y[25] stay
// register-resident (at bounds=5 / budget 102 the compiler demoted u[] to
// per-iteration LDS re-reads -- VGPR_Count was 48).
// ---------------------------------------------------------------------------
__global__ __launch_bounds__(256, 4)
void fused_gaunt_kernel(const float* __restrict__ x,
                        const float* __restrict__ norm_w,
                        const float* __restrict__ norm_b,
                        const float* __restrict__ w1,
                        const float* __restrict__ b1,
                        const float* __restrict__ tp_w,
                        const float* __restrict__ w2,
                        const float* __restrict__ b2,
                        float* __restrict__ out) {
  __shared__ float sA[L2C*PADR];   // 14400 B (x, then normalized h in place)
  __shared__ float sB[L2C*PADR];   // 14400 B (lin1 out / TP in place)
  __shared__ float sScr[4];

  const int t = threadIdx.x;
  const int n = blockIdx.x;
  const float* xn = x   + (size_t)n * (L2C*CCH);
  float*       on = out + (size_t)n * (L2C*CCH);

  // ---- stage: x -> sA (padded quarters)
  for (int e = t; e < (L2C*CCH)/4; e += 256) {
    const int i = e >> 5, c = (e & 31) << 2;
    *(float4*)&sA[i*PADR + pidx(c)] = ((const float4*)xn)[e];
  }
  __syncthreads();

  // ---- LN statistics
  float v0 = (t < CCH) ? sA[pidx(t)] : 0.f;
  const float mean0 = block_sum(v0, sScr, t) * (1.f/CCH);
  float ss = 0.f;
  for (int e = t; e < L2C*CCH; e += 256) {
    const float val = sA[(e >> 7)*PADR + pidx(e & 127)];
    ss = fmaf(val, val, ss);
  }
  const float s2 = block_sum(ss, sScr, t);
  const float var = (s2 - CCH*mean0*mean0) * (1.f/(L2C*CCH));
  const float inv = rsqrtf(var + 1e-5f);

  // ---- materialize normalized h in place
  for (int e = t; e < L2C*CCH; e += 256) {
    const int i = e >> 7, c = e & 127;
    float val = sA[i*PADR + pidx(c)];
    if (i == 0) val -= mean0;
    val *= inv * norm_w[lof_of(i)*CCH + c];
    if (i == 0) val += norm_b[c];
    sA[i*PADR + pidx(c)] = val;
  }
  __syncthreads();

  // ---- SO3Linear 1 (disjoint sB rows per degree; one sync at end)
  so3lin<0,false>(sA, sB, w1, b1, nullptr, nullptr, t);
  so3lin<1,false>(sA, sB, w1, b1, nullptr, nullptr, t);
  so3lin<2,false>(sA, sB, w1, b1, nullptr, nullptr, t);
  so3lin<3,false>(sA, sB, w1, b1, nullptr, nullptr, t);
  so3lin<4,false>(sA, sB, w1, b1, nullptr, nullptr, t);
  __syncthreads();

  // ---- Gaunt self-TP: 128-point exact grid, folded 4x by theta-mirror
  // (sgn_i = (-1)^(l+|m|)) and phi->phi+pi (sig_i = (-1)^|m|).
  // Classes: A(+,+)={0,4,6,8,16,18,20,22,24} B(+,-)={1,3,9,11,13,15}
  //          C(-,+)={2,10,12,14}             D(-,-)={5,7,17,19,21,23}
  // f(+t,p)=A+B+C+D  f(+t,p+8)=A-B+C-D  f(-t,p)=A+B-C-D  f(-t,p+8)=A-B-C+D
  // Y rows come straight from constexpr G_Y with wave-uniform indices ->
  // scalar (s_load) reads; no LDS copy.
  {
    const int c = t & 127;
    const int gg = t >> 7;                                   // wave-uniform
    const int ggu = __builtin_amdgcn_readfirstlane(gg);      // force SGPR
    float u[25], y[25];
#pragma unroll
    for (int i = 0; i < 25; ++i) { u[i] = sB[i*PADR + pidx(c)]; y[i] = 0.f; }
    // Pin u[] into VGPRs: opaque to the compiler so it cannot demote them
    // back to per-iteration LDS re-reads (the VGPR_Count=48 pathology).
#pragma unroll
    for (int i = 0; i < 25; ++i) asm volatile("" : "+v"(u[i]));
    __syncthreads();   // all u reads complete before sB partial overwrite
#pragma unroll
    for (int tt2 = 0; tt2 < 2; ++tt2) {
      const int tt = ggu*2 + tt2;
      const float wq = G_Y.wq[tt];
      for (int pp = 0; pp < NPHH; ++pp) {
        const float* yr = &G_Y.y[(tt*NPHH + pp)*YP];
        // class partial dot-products (A split for ILP)
        float A0 = u[ 0]*yr[0];
        A0 = fmaf(u[ 4], yr[ 4], A0); A0 = fmaf(u[ 6], yr[ 6], A0);
        A0 = fmaf(u[ 8], yr[ 8], A0); A0 = fmaf(u[24], yr[24], A0);
        float A1 = u[16]*yr[16];
        A1 = fmaf(u[18], yr[18], A1); A1 = fmaf(u[20], yr[20], A1);
        A1 = fmaf(u[22], yr[22], A1);
        float B = u[ 1]*yr[1];
        B = fmaf(u[ 3], yr[ 3], B); B = fmaf(u[ 9], yr[ 9], B);
        B = fmaf(u[11], yr[11], B); B = fmaf(u[13], yr[13], B);
        B = fmaf(u[15], yr[15], B);
        float C = u[ 2]*yr[2];
        C = fmaf(u[10], yr[10], C); C = fmaf(u[12], yr[12], C);
        C = fmaf(u[14], yr[14], C);
        float D = u[ 5]*yr[5];
        D = fmaf(u[ 7], yr[ 7], D); D = fmaf(u[17], yr[17], D);
        D = fmaf(u[19], yr[19], D); D = fmaf(u[21], yr[21], D);
        D = fmaf(u[23], yr[23], D);
        const float A  = A0 + A1;
        const float tp = A + B, tm = A - B, up = C + D, um = C - D;
        const float f1 = tp + up, f3 = tp - up;   // (+t,p), (-t,p)
        const float f2 = tm + um, f4 = tm - um;   // (+t,p+8), (-t,p+8)
        const float s1 = f1*f1, s2v = f2*f2, s3 = f3*f3, s4 = f4*f4;
        const float p = s1 + s2v, q = s1 - s2v, r = s3 + s4, t4 = s3 - s4;
        const float cA = wq*(p + r), cC = wq*(p - r);
        const float cB = wq*(q + t4), cD = wq*(q - t4);
        y[ 0] = fmaf(cA, yr[ 0], y[ 0]); y[ 1] = fmaf(cB, yr[ 1], y[ 1]);
        y[ 2] = fmaf(cC, yr[ 2], y[ 2]); y[ 3] = fmaf(cB, yr[ 3], y[ 3]);
        y[ 4] = fmaf(cA, yr[ 4], y[ 4]); y[ 5] = fmaf(cD, yr[ 5], y[ 5]);
        y[ 6] = fmaf(cA, yr[ 6], y[ 6]); y[ 7] = fmaf(cD, yr[ 7], y[ 7]);
        y[ 8] = fmaf(cA, yr[ 8], y[ 8]); y[ 9] = fmaf(cB, yr[ 9], y[ 9]);
        y[10] = fmaf(cC, yr[10], y[10]); y[11] = fmaf(cB, yr[11], y[11]);
        y[12] = fmaf(cC, yr[12], y[12]); y[13] = fmaf(cB, yr[13], y[13]);
        y[14] = fmaf(cC, yr[14], y[14]); y[15] = fmaf(cB, yr[15], y[15]);
        y[16] = fmaf(cA, yr[16], y[16]); y[17] = fmaf(cD, yr[17], y[17]);
        y[18] = fmaf(cA, yr[18], y[18]); y[19] = fmaf(cD, yr[19], y[19]);
        y[20] = fmaf(cA, yr[20], y[20]); y[21] = fmaf(cD, yr[21], y[21]);
        y[22] = fmaf(cA, yr[22], y[22]); y[23] = fmaf(cD, yr[23], y[23]);
        y[24] = fmaf(cA, yr[24], y[24]);
      }
    }
    if (gg == 1) {
#pragma unroll
      for (int i = 0; i < 25; ++i) sB[i*PADR + pidx(c)] = y[i];
    }
    __syncthreads();
    if (gg == 0) {
#pragma unroll
      for (int i = 0; i < 25; ++i)
        sB[i*PADR + pidx(c)] = (y[i] + sB[i*PADR + pidx(c)]) * tp_w[lof_of(i)*CCH + c];
    }
    __syncthreads();
  }

  // ---- SO3Linear 2 + bias(l=0) + residual (global re-read) -> out
  so3lin<0,true>(sB, nullptr, w2, b2, xn, on, t);
  so3lin<1,true>(sB, nullptr, w2, b2, xn, on, t);
  so3lin<2,true>(sB, nullptr, w2, b2, xn, on, t);
  so3lin<3,true>(sB, nullptr, w2, b2, xn, on, t);
  so3lin<4,true>(sB, nullptr, w2, b2, xn, on, t);
}

extern "C" void kernel_launch(void* const* d_in, const int* in_sizes, int n_in,
                              void* d_out, int out_size, void* d_ws, size_t ws_size,
                              hipStream_t stream) {
  (void)n_in; (void)out_size; (void)d_ws; (void)ws_size;
  const float* x      = (const float*)d_in[0];
  // d_in[1] = batch (int32) -- only feeds drop_path(rate=0), unused
  const float* norm_w = (const float*)d_in[2];
  const float* norm_b = (const float*)d_in[3];
  const float* w1     = (const float*)d_in[4];
  const float* b1     = (const float*)d_in[5];
  const float* tp_w   = (const float*)d_in[6];
  const float* w2     = (const float*)d_in[7];
  const float* b2     = (const float*)d_in[8];
  float* out  = (float*)d_out;

  const int N = in_sizes[0] / (L2C*CCH);

  fused_gaunt_kernel<<<dim3(N), dim3(256), 0, stream>>>(
      x, norm_w, norm_b, w1, b1, tp_w, w2, b2, out);
}